// Round 1
// baseline (721.991 us; speedup 1.0000x reference)
//
#include <hip/hip_runtime.h>

#define E_ 16
#define KSEL 2
#define DIN 256
#define DH 512
#define DOUT 256
#define BTOK 32768

typedef _Float16 half8 __attribute__((ext_vector_type(8)));
typedef float float4v __attribute__((ext_vector_type(4)));

// ---------------- workspace layout (bytes) ----------------
#define OFF_P1      0u                      // packed W1 fp16: E*8*32*512 halfs = 4 MB
#define OFF_P2      4194304u                // packed W2 fp16: E*16*16*512 halfs = 4 MB
#define OFF_XBF     8388608u                // x fp16: B*256 halfs = 16 MB
#define OFF_TIDX    25165824u               // top idx int[B*2]
#define OFF_TW      25427968u               // top w  float[B*2]
#define OFF_STOK    25690112u               // sorted token ids int[B*2]
#define OFF_SW      25952256u               // sorted weights float[B*2]
#define OFF_CNT     26214400u               // counts int[16]
#define OFF_OFFS    26214528u               // offsets int[17]
#define OFF_CUR     26214656u               // cursors int[16]

// ---------------- init: zero out + counts ----------------
__global__ __launch_bounds__(256) void init_kernel(float* out, int* counts) {
    int g = blockIdx.x * 256 + threadIdx.x;           // 8192 blocks -> 2,097,152 float4
    ((float4v*)out)[g] = (float4v){0.f, 0.f, 0.f, 0.f};
    if (blockIdx.x == 0 && threadIdx.x < 16) counts[threadIdx.x] = 0;
}

// ---------------- pack W1/W2 into MFMA B-fragment layout (fp16) ----------------
// B-frag for 16x16x32: lane holds B[k = kt*32 + (lane>>4)*8 + j][n = nt*16 + (lane&15)], j=0..7
__global__ __launch_bounds__(64) void pack_kernel(const float* __restrict__ W1,
                                                  const float* __restrict__ W2,
                                                  _Float16* __restrict__ p1,
                                                  _Float16* __restrict__ p2) {
    int bid = blockIdx.x;
    int l = threadIdx.x;
    int quad = l >> 4, l15 = l & 15;
    if (bid < 4096) {              // W1: bid = (e*8 + kt)*32 + nt
        int nt = bid & 31, kt = (bid >> 5) & 7, e = bid >> 8;
        half8 v;
#pragma unroll
        for (int j = 0; j < 8; ++j) {
            int i = kt * 32 + quad * 8 + j;
            int h = nt * 16 + l15;
            v[j] = (_Float16)W1[(e * DIN + i) * DH + h];
        }
        ((half8*)p1)[bid * 64 + l] = v;
    } else {                       // W2: bid-4096 = (e*16 + kt2)*16 + nt2
        int b2i = bid - 4096;
        int nt = b2i & 15, kt = (b2i >> 4) & 15, e = b2i >> 8;
        half8 v;
#pragma unroll
        for (int j = 0; j < 8; ++j) {
            int i = kt * 32 + quad * 8 + j;
            int h = nt * 16 + l15;
            v[j] = (_Float16)W2[(e * DH + i) * DOUT + h];
        }
        ((half8*)p2)[b2i * 64 + l] = v;
    }
}

// ---------------- x -> fp16 ----------------
__global__ __launch_bounds__(256) void xbf_kernel(const float* __restrict__ x,
                                                  _Float16* __restrict__ xh) {
    int g = blockIdx.x * 256 + threadIdx.x;           // 4096 blocks, 8 elems/thread
    float4v a = ((const float4v*)x)[2 * g];
    float4v b = ((const float4v*)x)[2 * g + 1];
    half8 v;
#pragma unroll
    for (int j = 0; j < 4; ++j) { v[j] = (_Float16)a[j]; v[4 + j] = (_Float16)b[j]; }
    ((half8*)xh)[g] = v;
}

// ---------------- gating: fp32 logits, top-2, renorm weights ----------------
__global__ __launch_bounds__(256) void gate_kernel(const float* __restrict__ x,
                                                   const float* __restrict__ Wg,
                                                   const float* __restrict__ bg,
                                                   int* __restrict__ tidx,
                                                   float* __restrict__ tw,
                                                   int* __restrict__ counts) {
    __shared__ float WgS[DIN * E_];                   // 16 KB, [i][e] row-major
    int tid = threadIdx.x;
#pragma unroll
    for (int i = 0; i < 4; ++i)
        ((float4v*)WgS)[tid + i * 256] = ((const float4v*)Wg)[tid + i * 256];
    __syncthreads();

    int tl = tid >> 2, q = tid & 3;                   // 64 tokens/block, 4 threads/token
    int b = blockIdx.x * 64 + tl;
    const float* xr = x + b * DIN + q * 64;

    float acc[16];
#pragma unroll
    for (int e = 0; e < 16; ++e) acc[e] = 0.f;

    for (int ii = 0; ii < 16; ++ii) {
        float4v xv = ((const float4v*)xr)[ii];
#pragma unroll
        for (int j = 0; j < 4; ++j) {
            const float4v* wrow = (const float4v*)&WgS[(q * 64 + ii * 4 + j) * 16];
            float xs = xv[j];
#pragma unroll
            for (int e4 = 0; e4 < 4; ++e4) {
                float4v w4 = wrow[e4];
                acc[e4 * 4 + 0] += xs * w4[0];
                acc[e4 * 4 + 1] += xs * w4[1];
                acc[e4 * 4 + 2] += xs * w4[2];
                acc[e4 * 4 + 3] += xs * w4[3];
            }
        }
    }
    // reduce the 4 quarter-partials (lanes differing in bits 0..1)
#pragma unroll
    for (int e = 0; e < 16; ++e) {
        acc[e] += __shfl_xor(acc[e], 1);
        acc[e] += __shfl_xor(acc[e], 2);
    }
    if (q == 0) {
        float m1 = -3.4e38f, m2 = -3.4e38f;
        int i1 = 0, i2 = 0;
#pragma unroll
        for (int e = 0; e < 16; ++e) {
            float v = acc[e] + bg[e];
            if (v > m1) { m2 = m1; i2 = i1; m1 = v; i1 = e; }
            else if (v > m2) { m2 = v; i2 = e; }
        }
        // renormalized top-2 softmax == softmax over the 2 logits
        float e2 = expf(m2 - m1);
        float w1 = 1.f / (1.f + e2);
        float w2 = e2 * w1;
        tidx[b * 2] = i1; tidx[b * 2 + 1] = i2;
        tw[b * 2] = w1;  tw[b * 2 + 1] = w2;
        atomicAdd(&counts[i1], 1);
        atomicAdd(&counts[i2], 1);
    }
}

// ---------------- scan (16 elems, one thread) ----------------
__global__ void scan_kernel(const int* __restrict__ counts, int* __restrict__ offsets,
                            int* __restrict__ cursor) {
    if (threadIdx.x == 0) {
        int run = 0;
        for (int e = 0; e < 16; ++e) { offsets[e] = run; cursor[e] = run; run += counts[e]; }
        offsets[16] = run;
    }
}

// ---------------- scatter assignments into per-expert lists ----------------
__global__ __launch_bounds__(256) void scatter_kernel(const int* __restrict__ tidx,
                                                      const float* __restrict__ tw,
                                                      int* __restrict__ cursor,
                                                      int* __restrict__ stok,
                                                      float* __restrict__ sw) {
    int g = blockIdx.x * 256 + threadIdx.x;           // 65536 assignments
    int e = tidx[g];
    int pos = atomicAdd(&cursor[e], 1);
    stok[pos] = g >> 1;
    sw[pos] = tw[g];
}

// ---------------- fused expert MLP: relu(X@W1+b1)@W2+b2, weighted atomic combine ----------------
__global__ __launch_bounds__(256) void mlp_kernel(const _Float16* __restrict__ xh,
                                                  const _Float16* __restrict__ p1,
                                                  const _Float16* __restrict__ p2,
                                                  const float* __restrict__ b1,
                                                  const float* __restrict__ b2,
                                                  const int* __restrict__ offsets,
                                                  const int* __restrict__ stok,
                                                  const float* __restrict__ sw,
                                                  float* __restrict__ out) {
    __shared__ _Float16 Hs[2][64][72];                // double-buffered H chunk, +8 pad
    const int e = blockIdx.y;
    const int off = offsets[e];
    const int ne = offsets[e + 1] - off;
    const int ts = blockIdx.x * 64;
    if (ts >= ne) return;
    const int rows = min(64, ne - ts);
    const int tid = threadIdx.x;
    const int wv = tid >> 6;
    const int l = tid & 63;
    const int l15 = l & 15;
    const int quad = l >> 4;

    // A-fragment row pointers (gathered tokens), clamped for partial tiles
    const half8* xp[4];
#pragma unroll
    for (int mt = 0; mt < 4; ++mt) {
        int r = mt * 16 + l15; if (r >= rows) r = rows - 1;
        int tok = stok[off + ts + r];
        xp[mt] = (const half8*)(xh + tok * DIN + quad * 8);
    }

    float4v y[4][4];
#pragma unroll
    for (int mt = 0; mt < 4; ++mt)
#pragma unroll
        for (int nt = 0; nt < 4; ++nt) y[mt][nt] = (float4v){0.f, 0.f, 0.f, 0.f};

    const half8* p1b = (const half8*)p1;
    const half8* p2b = (const half8*)p2;

    for (int c = 0; c < 8; ++c) {                     // D_H chunks of 64
        const int ntg = c * 4 + wv;                   // this wave's h-col tile (of 32)
        float4v h[4];
#pragma unroll
        for (int mt = 0; mt < 4; ++mt) h[mt] = (float4v){0.f, 0.f, 0.f, 0.f};
#pragma unroll
        for (int kt = 0; kt < 8; ++kt) {              // K = D_IN = 256
            half8 bf = p1b[((e * 8 + kt) * 32 + ntg) * 64 + l];
#pragma unroll
            for (int mt = 0; mt < 4; ++mt) {
                half8 af = xp[mt][kt * 4];
                h[mt] = __builtin_amdgcn_mfma_f32_16x16x32_f16(af, bf, h[mt], 0, 0, 0);
            }
        }
        float b1v = b1[e * DH + ntg * 16 + l15];
        const int buf = c & 1;
#pragma unroll
        for (int mt = 0; mt < 4; ++mt)
#pragma unroll
            for (int r = 0; r < 4; ++r) {
                float v = h[mt][r] + b1v;
                v = v > 0.f ? v : 0.f;                // ReLU
                Hs[buf][mt * 16 + quad * 4 + r][wv * 16 + l15] = (_Float16)v;
            }
        __syncthreads();
#pragma unroll
        for (int kk = 0; kk < 2; ++kk) {              // GEMM2 over this chunk, K=64
            const int kt2 = c * 2 + kk;
            half8 af2[4];
#pragma unroll
            for (int mt = 0; mt < 4; ++mt)
                af2[mt] = *(const half8*)&Hs[buf][mt * 16 + l15][kk * 32 + quad * 8];
#pragma unroll
            for (int nt = 0; nt < 4; ++nt) {
                half8 bf2 = p2b[((e * 16 + kt2) * 16 + (wv * 4 + nt)) * 64 + l];
#pragma unroll
                for (int mt = 0; mt < 4; ++mt)
                    y[mt][nt] = __builtin_amdgcn_mfma_f32_16x16x32_f16(af2[mt], bf2, y[mt][nt], 0, 0, 0);
            }
        }
    }
    // epilogue: + b2, scale by routing weight, atomic combine
#pragma unroll
    for (int mt = 0; mt < 4; ++mt) {
#pragma unroll
        for (int r = 0; r < 4; ++r) {
            int rg = mt * 16 + quad * 4 + r;
            if (rg < rows) {
                int tok = stok[off + ts + rg];
                float wt = sw[off + ts + rg];
#pragma unroll
                for (int nt = 0; nt < 4; ++nt) {
                    int col = (wv * 4 + nt) * 16 + l15;
                    atomicAdd(&out[tok * DOUT + col], wt * (y[mt][nt][r] + b2[e * DOUT + col]));
                }
            }
        }
    }
}

extern "C" void kernel_launch(void* const* d_in, const int* in_sizes, int n_in,
                              void* d_out, int out_size, void* d_ws, size_t ws_size,
                              hipStream_t stream) {
    const float* x  = (const float*)d_in[0];
    const float* Wg = (const float*)d_in[1];
    const float* bg = (const float*)d_in[2];
    const float* W1 = (const float*)d_in[3];
    const float* b1 = (const float*)d_in[4];
    const float* W2 = (const float*)d_in[5];
    const float* b2 = (const float*)d_in[6];
    float* out = (float*)d_out;

    char* ws = (char*)d_ws;
    _Float16* p1  = (_Float16*)(ws + OFF_P1);
    _Float16* p2  = (_Float16*)(ws + OFF_P2);
    _Float16* xh  = (_Float16*)(ws + OFF_XBF);
    int* tidx     = (int*)(ws + OFF_TIDX);
    float* tw     = (float*)(ws + OFF_TW);
    int* stok     = (int*)(ws + OFF_STOK);
    float* swp    = (float*)(ws + OFF_SW);
    int* counts   = (int*)(ws + OFF_CNT);
    int* offsets  = (int*)(ws + OFF_OFFS);
    int* cursor   = (int*)(ws + OFF_CUR);

    init_kernel<<<dim3(8192), dim3(256), 0, stream>>>(out, counts);
    pack_kernel<<<dim3(8192), dim3(64), 0, stream>>>(W1, W2, p1, p2);
    xbf_kernel<<<dim3(4096), dim3(256), 0, stream>>>(x, xh);
    gate_kernel<<<dim3(512), dim3(256), 0, stream>>>(x, Wg, bg, tidx, tw, counts);
    scan_kernel<<<dim3(1), dim3(64), 0, stream>>>(counts, offsets, cursor);
    scatter_kernel<<<dim3(256), dim3(256), 0, stream>>>(tidx, tw, cursor, stok, swp);
    mlp_kernel<<<dim3(512, 16), dim3(256), 0, stream>>>(xh, p1, p2, b1, b2, offsets,
                                                        stok, swp, out);
}

// Round 2
// 230.923 us; speedup vs baseline: 3.1265x; 3.1265x over previous
//
#include <hip/hip_runtime.h>

#define E_ 16
#define DIN 256
#define DH 512
#define DOUT 256
#define BTOK 32768

typedef _Float16 half8 __attribute__((ext_vector_type(8)));
typedef _Float16 half4v __attribute__((ext_vector_type(4)));
typedef float float4v __attribute__((ext_vector_type(4)));

// ---------------- workspace layout (bytes) ----------------
#define OFF_P1      0u            // packed W1 fp16: 16*8*32*64*16B = 4 MB
#define OFF_P2      4194304u      // packed W2 fp16: 4 MB
#define OFF_XH      8388608u      // x fp16: 32768*256*2 = 16 MB
#define OFF_SCR     25165824u     // per-assignment weighted out, fp16: 65536*256*2 = 32 MB
#define OFF_TIDX    58720256u     // int[B*2]
#define OFF_TW      58982400u     // float[B*2]
#define OFF_STOK    59244544u     // int[65536] token id per sorted assignment
#define OFF_SW      59506688u     // float[65536] routing weight per sorted assignment
#define OFF_APOS    59768832u     // int[B*2]: assignment g -> sorted pos
#define OFF_CNT     60030976u     // int[16]
#define OFF_OFFS    60031104u     // int[17]
#define OFF_CUR     60031232u     // int[16]

// ---------------- pack W1/W2 into MFMA B-fragment layout (fp16) ----------------
// B-frag 16x16x32: lane l holds B[k = kt*32 + (l>>4)*8 + j][n = nt*16 + (l&15)]
__global__ __launch_bounds__(64) void pack_kernel(const float* __restrict__ W1,
                                                  const float* __restrict__ W2,
                                                  _Float16* __restrict__ p1,
                                                  _Float16* __restrict__ p2) {
    int bid = blockIdx.x;
    int l = threadIdx.x;
    int quad = l >> 4, l15 = l & 15;
    if (bid < 4096) {              // W1: bid = (e*8 + kt)*32 + nt
        int nt = bid & 31, kt = (bid >> 5) & 7, e = bid >> 8;
        half8 v;
#pragma unroll
        for (int j = 0; j < 8; ++j)
            v[j] = (_Float16)W1[(e * DIN + kt * 32 + quad * 8 + j) * DH + nt * 16 + l15];
        ((half8*)p1)[bid * 64 + l] = v;
    } else {                       // W2: bid-4096 = (e*16 + kt2)*16 + nt2
        int b2i = bid - 4096;
        int nt = b2i & 15, kt = (b2i >> 4) & 15, e = b2i >> 8;
        half8 v;
#pragma unroll
        for (int j = 0; j < 8; ++j)
            v[j] = (_Float16)W2[(e * DH + kt * 32 + quad * 8 + j) * DOUT + nt * 16 + l15];
        ((half8*)p2)[b2i * 64 + l] = v;
    }
}

// ---------------- x -> fp16 (+ zero the 16 expert counters) ----------------
__global__ __launch_bounds__(256) void xbf_kernel(const float* __restrict__ x,
                                                  _Float16* __restrict__ xh,
                                                  int* __restrict__ counts) {
    int g = blockIdx.x * 256 + threadIdx.x;
    float4v a = ((const float4v*)x)[2 * g];
    float4v b = ((const float4v*)x)[2 * g + 1];
    half8 v;
#pragma unroll
    for (int j = 0; j < 4; ++j) { v[j] = (_Float16)a[j]; v[4 + j] = (_Float16)b[j]; }
    ((half8*)xh)[g] = v;
    if (blockIdx.x == 0 && threadIdx.x < 16) counts[threadIdx.x] = 0;
}

// ---------------- gating: fp32 logits, top-2, renorm; LDS histogram ----------------
__global__ __launch_bounds__(256) void gate_kernel(const float* __restrict__ x,
                                                   const float* __restrict__ Wg,
                                                   const float* __restrict__ bg,
                                                   int* __restrict__ tidx,
                                                   float* __restrict__ tw,
                                                   int* __restrict__ counts) {
    __shared__ float WgS[DIN * E_];                   // 16 KB
    __shared__ int hcnt[16];
    int tid = threadIdx.x;
    if (tid < 16) hcnt[tid] = 0;
#pragma unroll
    for (int i = 0; i < 4; ++i)
        ((float4v*)WgS)[tid + i * 256] = ((const float4v*)Wg)[tid + i * 256];
    __syncthreads();

    int tl = tid >> 2, q = tid & 3;                   // 64 tokens/block
    int b = blockIdx.x * 64 + tl;
    const float* xr = x + b * DIN + q * 64;

    float acc[16];
#pragma unroll
    for (int e = 0; e < 16; ++e) acc[e] = 0.f;

    for (int ii = 0; ii < 16; ++ii) {
        float4v xv = ((const float4v*)xr)[ii];
#pragma unroll
        for (int j = 0; j < 4; ++j) {
            const float4v* wrow = (const float4v*)&WgS[(q * 64 + ii * 4 + j) * 16];
            float xs = xv[j];
#pragma unroll
            for (int e4 = 0; e4 < 4; ++e4) {
                float4v w4 = wrow[e4];
                acc[e4 * 4 + 0] += xs * w4[0];
                acc[e4 * 4 + 1] += xs * w4[1];
                acc[e4 * 4 + 2] += xs * w4[2];
                acc[e4 * 4 + 3] += xs * w4[3];
            }
        }
    }
#pragma unroll
    for (int e = 0; e < 16; ++e) {
        acc[e] += __shfl_xor(acc[e], 1);
        acc[e] += __shfl_xor(acc[e], 2);
    }
    if (q == 0) {
        float m1 = -3.4e38f, m2 = -3.4e38f;
        int i1 = 0, i2 = 0;
#pragma unroll
        for (int e = 0; e < 16; ++e) {
            float v = acc[e] + bg[e];
            if (v > m1) { m2 = m1; i2 = i1; m1 = v; i1 = e; }
            else if (v > m2) { m2 = v; i2 = e; }
        }
        float e2 = __expf(m2 - m1);
        float w1 = 1.f / (1.f + e2);
        tidx[b * 2] = i1; tidx[b * 2 + 1] = i2;
        tw[b * 2] = w1;  tw[b * 2 + 1] = e2 * w1;
        atomicAdd(&hcnt[i1], 1);
        atomicAdd(&hcnt[i2], 1);
    }
    __syncthreads();
    if (tid < 16) atomicAdd(&counts[tid], hcnt[tid]);
}

// ---------------- scan ----------------
__global__ void scan_kernel(const int* __restrict__ counts, int* __restrict__ offsets,
                            int* __restrict__ cursor) {
    if (threadIdx.x == 0) {
        int run = 0;
        for (int e = 0; e < 16; ++e) { offsets[e] = run; cursor[e] = run; run += counts[e]; }
        offsets[16] = run;
    }
}

// ---------------- scatter: block-ranked, 16 global atomics per block ----------------
__global__ __launch_bounds__(256) void scatter_kernel(const int* __restrict__ tidx,
                                                      const float* __restrict__ tw,
                                                      int* __restrict__ cursor,
                                                      int* __restrict__ stok,
                                                      float* __restrict__ sw,
                                                      int* __restrict__ apos) {
    __shared__ int lc[16];
    __shared__ int lbase[16];
    int tid = threadIdx.x;
    if (tid < 16) lc[tid] = 0;
    __syncthreads();
    int g = blockIdx.x * 256 + tid;
    int e = tidx[g];
    int rank = atomicAdd(&lc[e], 1);
    __syncthreads();
    if (tid < 16) lbase[tid] = atomicAdd(&cursor[tid], lc[tid]);
    __syncthreads();
    int pos = lbase[e] + rank;
    stok[pos] = g >> 1;
    sw[pos] = tw[g];
    apos[g] = pos;
}

// ---------------- H LDS: 64x512 fp16, XOR-swizzled in 16B chunks ----------------
__device__ __forceinline__ int hsw(int row, int col) {
    return row * 512 + ((((col >> 3) ^ (row & 7)) << 3) | (col & 7));
}

// ---------------- fused expert MLP, two-phase, no atomics ----------------
__global__ __launch_bounds__(256, 2) void mlp_kernel(const _Float16* __restrict__ xh,
                                                     const _Float16* __restrict__ p1,
                                                     const _Float16* __restrict__ p2,
                                                     const float* __restrict__ b1,
                                                     const float* __restrict__ b2,
                                                     const int* __restrict__ offsets,
                                                     const int* __restrict__ stok,
                                                     const float* __restrict__ sw,
                                                     _Float16* __restrict__ scr) {
    __shared__ _Float16 Hs[64 * 512];                 // 64 KB, swizzled
    const int e = blockIdx.y;
    const int off = offsets[e];
    const int ne = offsets[e + 1] - off;
    const int ts = blockIdx.x * 64;
    if (ts >= ne) return;
    const int rows = min(64, ne - ts);
    const int tid = threadIdx.x;
    const int wv = tid >> 6;
    const int l = tid & 63;
    const int l15 = l & 15;
    const int quad = l >> 4;

    // gathered A-row base pointers (clamped for partial tiles)
    const _Float16* xp[4];
#pragma unroll
    for (int mt = 0; mt < 4; ++mt) {
        int r = mt * 16 + l15; if (r >= rows) r = rows - 1;
        xp[mt] = xh + stok[off + ts + r] * DIN + quad * 8;
    }

    const half8* p1b = (const half8*)p1;
    const half8* p2b = (const half8*)p2;

    // ---- phase 1: H = relu(X @ W1 + b1), wave wv covers DH cols [wv*128, wv*128+128) ----
    float4v acc1[4][8];
#pragma unroll
    for (int mt = 0; mt < 4; ++mt)
#pragma unroll
        for (int nt = 0; nt < 8; ++nt) acc1[mt][nt] = (float4v){0.f, 0.f, 0.f, 0.f};

#pragma unroll
    for (int kt = 0; kt < 8; ++kt) {
        half8 af[4];
#pragma unroll
        for (int mt = 0; mt < 4; ++mt) af[mt] = *(const half8*)(xp[mt] + kt * 32);
#pragma unroll
        for (int nt = 0; nt < 8; ++nt) {
            half8 bf = p1b[((e * 8 + kt) * 32 + wv * 8 + nt) * 64 + l];
#pragma unroll
            for (int mt = 0; mt < 4; ++mt)
                acc1[mt][nt] = __builtin_amdgcn_mfma_f32_16x16x32_f16(af[mt], bf, acc1[mt][nt], 0, 0, 0);
        }
    }
#pragma unroll
    for (int nt = 0; nt < 8; ++nt) {
        float b1v = b1[e * DH + (wv * 8 + nt) * 16 + l15];
        int col = (wv * 8 + nt) * 16 + l15;
#pragma unroll
        for (int mt = 0; mt < 4; ++mt)
#pragma unroll
            for (int r = 0; r < 4; ++r) {
                float v = acc1[mt][nt][r] + b1v;
                Hs[hsw(mt * 16 + quad * 4 + r, col)] = (_Float16)(v > 0.f ? v : 0.f);
            }
    }
    __syncthreads();

    // ---- phase 2: Y = H @ W2, wave wv covers DOUT cols [wv*64, wv*64+64) ----
    float4v acc2[4][4];
#pragma unroll
    for (int mt = 0; mt < 4; ++mt)
#pragma unroll
        for (int nt = 0; nt < 4; ++nt) acc2[mt][nt] = (float4v){0.f, 0.f, 0.f, 0.f};

#pragma unroll
    for (int kt2 = 0; kt2 < 16; ++kt2) {
        half8 af2[4];
#pragma unroll
        for (int mt = 0; mt < 4; ++mt) {
            int row = mt * 16 + l15;
            int chunk = (kt2 * 4 + quad) ^ (row & 7);
            af2[mt] = *(const half8*)&Hs[row * 512 + chunk * 8];
        }
#pragma unroll
        for (int nt = 0; nt < 4; ++nt) {
            half8 bf2 = p2b[((e * 16 + kt2) * 16 + wv * 4 + nt) * 64 + l];
#pragma unroll
            for (int mt = 0; mt < 4; ++mt)
                acc2[mt][nt] = __builtin_amdgcn_mfma_f32_16x16x32_f16(af2[mt], bf2, acc2[mt][nt], 0, 0, 0);
        }
    }

    // ---- epilogue: + b2, apply routing weight, store fp16 to scratch (sorted order) ----
#pragma unroll
    for (int mt = 0; mt < 4; ++mt)
#pragma unroll
        for (int r = 0; r < 4; ++r) {
            int rg = mt * 16 + quad * 4 + r;
            if (rg < rows) {
                int pos = off + ts + rg;
                float wt = sw[pos];
#pragma unroll
                for (int nt = 0; nt < 4; ++nt) {
                    int col = (wv * 4 + nt) * 16 + l15;
                    scr[pos * DOUT + col] = (_Float16)(wt * (acc2[mt][nt][r] + b2[e * DOUT + col]));
                }
            }
        }
}

// ---------------- combine: out[t] = scr[pos0] + scr[pos1] ----------------
__global__ __launch_bounds__(256) void combine_kernel(const _Float16* __restrict__ scr,
                                                      const int* __restrict__ apos,
                                                      float* __restrict__ out) {
    int wv = threadIdx.x >> 6;
    int l = threadIdx.x & 63;
    int t = blockIdx.x * 4 + wv;
    int p0 = apos[2 * t], p1 = apos[2 * t + 1];
    half4v a = *(const half4v*)(scr + p0 * DOUT + l * 4);
    half4v b = *(const half4v*)(scr + p1 * DOUT + l * 4);
    float4v o;
#pragma unroll
    for (int j = 0; j < 4; ++j) o[j] = (float)a[j] + (float)b[j];
    ((float4v*)(out + t * DOUT))[l] = o;
}

extern "C" void kernel_launch(void* const* d_in, const int* in_sizes, int n_in,
                              void* d_out, int out_size, void* d_ws, size_t ws_size,
                              hipStream_t stream) {
    const float* x  = (const float*)d_in[0];
    const float* Wg = (const float*)d_in[1];
    const float* bg = (const float*)d_in[2];
    const float* W1 = (const float*)d_in[3];
    const float* b1 = (const float*)d_in[4];
    const float* W2 = (const float*)d_in[5];
    const float* b2 = (const float*)d_in[6];
    float* out = (float*)d_out;

    char* ws = (char*)d_ws;
    _Float16* p1  = (_Float16*)(ws + OFF_P1);
    _Float16* p2  = (_Float16*)(ws + OFF_P2);
    _Float16* xh  = (_Float16*)(ws + OFF_XH);
    _Float16* scr = (_Float16*)(ws + OFF_SCR);
    int* tidx     = (int*)(ws + OFF_TIDX);
    float* tw     = (float*)(ws + OFF_TW);
    int* stok     = (int*)(ws + OFF_STOK);
    float* swp    = (float*)(ws + OFF_SW);
    int* apos     = (int*)(ws + OFF_APOS);
    int* counts   = (int*)(ws + OFF_CNT);
    int* offsets  = (int*)(ws + OFF_OFFS);
    int* cursor   = (int*)(ws + OFF_CUR);

    pack_kernel<<<dim3(8192), dim3(64), 0, stream>>>(W1, W2, p1, p2);
    xbf_kernel<<<dim3(4096), dim3(256), 0, stream>>>(x, xh, counts);
    gate_kernel<<<dim3(512), dim3(256), 0, stream>>>(x, Wg, bg, tidx, tw, counts);
    scan_kernel<<<dim3(1), dim3(64), 0, stream>>>(counts, offsets, cursor);
    scatter_kernel<<<dim3(256), dim3(256), 0, stream>>>(tidx, tw, cursor, stok, swp, apos);
    mlp_kernel<<<dim3(512, 16), dim3(256), 0, stream>>>(xh, p1, p2, b1, b2, offsets,
                                                        stok, swp, scr);
    combine_kernel<<<dim3(8192), dim3(256), 0, stream>>>(scr, apos, out);
}

// Round 3
// 227.950 us; speedup vs baseline: 3.1673x; 1.0130x over previous
//
#include <hip/hip_runtime.h>

#define E_ 16
#define DIN 256
#define DH 512
#define DOUT 256
#define BTOK 32768
#define HPAD 520   // H row stride in halfs (512 + 8)

typedef _Float16 half8 __attribute__((ext_vector_type(8)));
typedef _Float16 half4v __attribute__((ext_vector_type(4)));
typedef float float4v __attribute__((ext_vector_type(4)));

// ---------------- workspace layout (bytes) ----------------
#define OFF_P1      0u            // packed W1 fp16: 4 MB
#define OFF_P2      4194304u      // packed W2 fp16: 4 MB
#define OFF_XH      8388608u      // x fp16: 16 MB
#define OFF_SCR     25165824u     // per-assignment weighted out fp16, token-slot-major: 32 MB
#define OFF_TIDX    58720256u     // int[B*2]
#define OFF_TW      58982400u     // float[B*2]
#define OFF_STOK    59244544u     // int[65536]: g = tok*2+slot per sorted assignment
#define OFF_SW      59506688u     // float[65536]
#define OFF_CNT     59768832u     // int[16]
#define OFF_OFFS    59768960u     // int[17]
#define OFF_CUR     59769088u     // int[16]
#define OFF_TMAP    59769216u     // int[1056] tile -> (e<<16)|tile_in_e
#define OFF_TMC     59773504u     // int[1] tile count

// ---------------- pack W1/W2 into MFMA fragment layout (fp16); zero counts ----------------
// frag (16x16x32): lane l holds M[k = (l>>4)*8 + j][n = (l&15)] per 32x16 tile
__global__ __launch_bounds__(256) void pack_kernel(const float* __restrict__ W1,
                                                   const float* __restrict__ W2,
                                                   _Float16* __restrict__ p1,
                                                   _Float16* __restrict__ p2,
                                                   int* __restrict__ counts) {
    int tid = threadIdx.x;
    int bid = blockIdx.x * 4 + (tid >> 6);
    int l = tid & 63;
    int quad = l >> 4, l15 = l & 15;
    if (blockIdx.x == 0 && tid < 16) counts[tid] = 0;
    if (bid < 4096) {              // W1: bid = (e*8 + kt)*32 + ht
        int ht = bid & 31, kt = (bid >> 5) & 7, e = bid >> 8;
        half8 v;
#pragma unroll
        for (int j = 0; j < 8; ++j)
            v[j] = (_Float16)W1[(e * DIN + kt * 32 + quad * 8 + j) * DH + ht * 16 + l15];
        ((half8*)p1)[bid * 64 + l] = v;
    } else {                       // W2: bid-4096 = (e*16 + kt2)*16 + ot
        int b2i = bid - 4096;
        int ot = b2i & 15, kt = (b2i >> 4) & 15, e = b2i >> 8;
        half8 v;
#pragma unroll
        for (int j = 0; j < 8; ++j)
            v[j] = (_Float16)W2[(e * DH + kt * 32 + quad * 8 + j) * DOUT + ot * 16 + l15];
        ((half8*)p2)[b2i * 64 + l] = v;
    }
}

// ---------------- gating (fp32) + x->fp16 conversion, fused ----------------
// 512 blocks x 256 thr; thread = (tg = tid>>3, q = tid&7); 2 tokens per tg, K-eighth per q.
__global__ __launch_bounds__(256) void gate_kernel(const float* __restrict__ x,
                                                   const float* __restrict__ Wg,
                                                   const float* __restrict__ bg,
                                                   _Float16* __restrict__ xh,
                                                   int* __restrict__ tidx,
                                                   float* __restrict__ tw,
                                                   int* __restrict__ counts) {
    __shared__ float WgS[DIN * E_];                   // 16 KB
    __shared__ int hcnt[16];
    int tid = threadIdx.x;
    if (tid < 16) hcnt[tid] = 0;
#pragma unroll
    for (int i = 0; i < 4; ++i)
        ((float4v*)WgS)[tid + i * 256] = ((const float4v*)Wg)[tid + i * 256];
    __syncthreads();

    int q = tid & 7, tg = tid >> 3;                   // 32 groups x 2 tokens = 64 tokens/block
    int t0 = blockIdx.x * 64 + tg * 2;

    float acc[2][16];
#pragma unroll
    for (int tt = 0; tt < 2; ++tt)
#pragma unroll
        for (int e = 0; e < 16; ++e) acc[tt][e] = 0.f;

#pragma unroll
    for (int ii = 0; ii < 8; ++ii) {                  // K-eighth: 32 floats = 8 float4
        int kb = q * 32 + ii * 4;
        float4v xv[2];
#pragma unroll
        for (int tt = 0; tt < 2; ++tt) {
            xv[tt] = *(const float4v*)&x[(t0 + tt) * DIN + kb];
            half4v hv;
#pragma unroll
            for (int j = 0; j < 4; ++j) hv[j] = (_Float16)xv[tt][j];
            *(half4v*)&xh[(t0 + tt) * DIN + kb] = hv;
        }
#pragma unroll
        for (int j = 0; j < 4; ++j) {
            const float4v* wrow = (const float4v*)&WgS[(kb + j) * 16];
            float4v w0 = wrow[0], w1 = wrow[1], w2 = wrow[2], w3 = wrow[3];
#pragma unroll
            for (int tt = 0; tt < 2; ++tt) {
                float xs = xv[tt][j];
#pragma unroll
                for (int c = 0; c < 4; ++c) {
                    acc[tt][0 + c]  += xs * w0[c];
                    acc[tt][4 + c]  += xs * w1[c];
                    acc[tt][8 + c]  += xs * w2[c];
                    acc[tt][12 + c] += xs * w3[c];
                }
            }
        }
    }
    // reduce across the 8 q-lanes
#pragma unroll
    for (int tt = 0; tt < 2; ++tt)
#pragma unroll
        for (int e = 0; e < 16; ++e) {
            acc[tt][e] += __shfl_xor(acc[tt][e], 1);
            acc[tt][e] += __shfl_xor(acc[tt][e], 2);
            acc[tt][e] += __shfl_xor(acc[tt][e], 4);
        }
    if (q == 0) {
#pragma unroll
        for (int tt = 0; tt < 2; ++tt) {
            int b = t0 + tt;
            float m1 = -3.4e38f, m2 = -3.4e38f;
            int i1 = 0, i2 = 0;
#pragma unroll
            for (int e = 0; e < 16; ++e) {
                float v = acc[tt][e] + bg[e];
                if (v > m1) { m2 = m1; i2 = i1; m1 = v; i1 = e; }
                else if (v > m2) { m2 = v; i2 = e; }
            }
            float e2 = __expf(m2 - m1);
            float w1 = 1.f / (1.f + e2);
            tidx[b * 2] = i1; tidx[b * 2 + 1] = i2;
            tw[b * 2] = w1;  tw[b * 2 + 1] = e2 * w1;
            atomicAdd(&hcnt[i1], 1);
            atomicAdd(&hcnt[i2], 1);
        }
    }
    __syncthreads();
    if (tid < 16) atomicAdd(&counts[tid], hcnt[tid]);
}

// ---------------- scan + tile map ----------------
__global__ void scan_kernel(const int* __restrict__ counts, int* __restrict__ offsets,
                            int* __restrict__ cursor, int* __restrict__ tmap,
                            int* __restrict__ tmc) {
    __shared__ int s_cnt[16];
    __shared__ int s_tstart[17];
    int tid = threadIdx.x;
    if (tid == 0) {
        int run = 0, trun = 0;
        for (int e = 0; e < 16; ++e) {
            int c = counts[e];
            s_cnt[e] = c;
            offsets[e] = run; cursor[e] = run; run += c;
            s_tstart[e] = trun; trun += (c + 63) >> 6;
        }
        offsets[16] = run;
        s_tstart[16] = trun;
        tmc[0] = trun;
    }
    __syncthreads();
    if (tid < 16) {
        int nt = (s_cnt[tid] + 63) >> 6;
        int base = s_tstart[tid];
        for (int t = 0; t < nt; ++t) tmap[base + t] = (tid << 16) | t;
    }
}

// ---------------- scatter: block-ranked, 16 global atomics per block ----------------
__global__ __launch_bounds__(256) void scatter_kernel(const int* __restrict__ tidx,
                                                      const float* __restrict__ tw,
                                                      int* __restrict__ cursor,
                                                      int* __restrict__ stok,
                                                      float* __restrict__ sw) {
    __shared__ int lc[16];
    __shared__ int lbase[16];
    int tid = threadIdx.x;
    if (tid < 16) lc[tid] = 0;
    __syncthreads();
    int g = blockIdx.x * 256 + tid;
    int e = tidx[g];
    int rank = atomicAdd(&lc[e], 1);
    __syncthreads();
    if (tid < 16) lbase[tid] = atomicAdd(&cursor[tid], lc[tid]);
    __syncthreads();
    int pos = lbase[e] + rank;
    stok[pos] = g;                 // g = tok*2 + slot
    sw[pos] = tw[g];
}

// ---------------- fused expert MLP: 512 thr, 8 waves, M=64, H[token][h] in LDS ----------------
__global__ __launch_bounds__(512, 4) void mlp_kernel(const _Float16* __restrict__ xh,
                                                     const _Float16* __restrict__ p1,
                                                     const _Float16* __restrict__ p2,
                                                     const float* __restrict__ b1,
                                                     const float* __restrict__ b2,
                                                     const int* __restrict__ offsets,
                                                     const int* __restrict__ stok,
                                                     const float* __restrict__ sw,
                                                     const int* __restrict__ tmap,
                                                     const int* __restrict__ tmc,
                                                     _Float16* __restrict__ scr) {
    __shared__ _Float16 Hs[64 * HPAD];                // 65 KB
    if ((int)blockIdx.x >= tmc[0]) return;
    const int tile = tmap[blockIdx.x];
    const int e = tile >> 16;
    const int ts = (tile & 0xffff) * 64;
    const int off = offsets[e];
    const int ne = offsets[e + 1] - off;
    const int rows = min(64, ne - ts);

    const int tid = threadIdx.x;
    const int w = tid >> 6;                           // wave 0..7
    const int l = tid & 63;
    const int l15 = l & 15;
    const int quad = l >> 4;

    // token row pointers for phase-1 B-frags (n = token), clamped
    const _Float16* tb[4];
#pragma unroll
    for (int nt = 0; nt < 4; ++nt) {
        int r = nt * 16 + l15; if (r >= rows) r = rows - 1;
        tb[nt] = xh + (stok[off + ts + r] >> 1) * DIN + quad * 8;
    }

    const half8* p1b = (const half8*)p1;
    const half8* p2b = (const half8*)p2;

    // ---- phase 1 (swapped operands): H^T tiles, wave w owns h-tiles w*4..w*4+3 ----
    float4v acc1[4][4];
#pragma unroll
    for (int mh = 0; mh < 4; ++mh)
#pragma unroll
        for (int nt = 0; nt < 4; ++nt) acc1[mh][nt] = (float4v){0.f, 0.f, 0.f, 0.f};

#pragma unroll
    for (int kt = 0; kt < 8; ++kt) {
        half8 bq[4];
#pragma unroll
        for (int nt = 0; nt < 4; ++nt) bq[nt] = *(const half8*)(tb[nt] + kt * 32);
#pragma unroll
        for (int mh = 0; mh < 4; ++mh) {
            half8 aw = p1b[((e * 8 + kt) * 32 + w * 4 + mh) * 64 + l];
#pragma unroll
            for (int nt = 0; nt < 4; ++nt)
                acc1[mh][nt] = __builtin_amdgcn_mfma_f32_16x16x32_f16(aw, bq[nt], acc1[mh][nt], 0, 0, 0);
        }
    }
    // bias + relu + store H[token][h] (b64 per acc tile)
#pragma unroll
    for (int mh = 0; mh < 4; ++mh) {
        int hb = (w * 4 + mh) * 16 + quad * 4;
        float4v b1q = *(const float4v*)&b1[e * DH + hb];
#pragma unroll
        for (int nt = 0; nt < 4; ++nt) {
            half4v hv;
#pragma unroll
            for (int r = 0; r < 4; ++r) {
                float v = acc1[mh][nt][r] + b1q[r];
                hv[r] = (_Float16)(v > 0.f ? v : 0.f);
            }
            *(half4v*)&Hs[(nt * 16 + l15) * HPAD + hb] = hv;
        }
    }
    __syncthreads();

    // ---- phase 2: Y = H @ W2, wave w owns out-col tiles w*2, w*2+1 ----
    float4v acc2[4][2];
#pragma unroll
    for (int mt = 0; mt < 4; ++mt)
#pragma unroll
        for (int n = 0; n < 2; ++n) acc2[mt][n] = (float4v){0.f, 0.f, 0.f, 0.f};

#pragma unroll
    for (int kt2 = 0; kt2 < 16; ++kt2) {
        half8 ha[4];
#pragma unroll
        for (int mt = 0; mt < 4; ++mt)
            ha[mt] = *(const half8*)&Hs[(mt * 16 + l15) * HPAD + kt2 * 32 + quad * 8];
#pragma unroll
        for (int n = 0; n < 2; ++n) {
            half8 bw = p2b[((e * 16 + kt2) * 16 + w * 2 + n) * 64 + l];
#pragma unroll
            for (int mt = 0; mt < 4; ++mt)
                acc2[mt][n] = __builtin_amdgcn_mfma_f32_16x16x32_f16(ha[mt], bw, acc2[mt][n], 0, 0, 0);
        }
    }

    // ---- epilogue: + b2, routing weight, fp16 store to token-slot-major scratch ----
    float b2v[2];
#pragma unroll
    for (int n = 0; n < 2; ++n) b2v[n] = b2[e * DOUT + (w * 2 + n) * 16 + l15];
#pragma unroll
    for (int mt = 0; mt < 4; ++mt)
#pragma unroll
        for (int r = 0; r < 4; ++r) {
            int row = mt * 16 + quad * 4 + r;
            if (row < rows) {
                int g = stok[off + ts + row];
                float wt = sw[off + ts + row];
#pragma unroll
                for (int n = 0; n < 2; ++n) {
                    int col = (w * 2 + n) * 16 + l15;
                    scr[g * DOUT + col] = (_Float16)(wt * (acc2[mt][n][r] + b2v[n]));
                }
            }
        }
}

// ---------------- combine: out[t] = scr[t*2] + scr[t*2+1], fully streaming ----------------
__global__ __launch_bounds__(256) void combine_kernel(const _Float16* __restrict__ scr,
                                                      float* __restrict__ out) {
    int wv = threadIdx.x >> 6;
    int l = threadIdx.x & 63;
    int t = blockIdx.x * 4 + wv;
    half4v a = ((const half4v*)(scr + t * 2 * DOUT))[l];
    half4v b = ((const half4v*)(scr + t * 2 * DOUT + DOUT))[l];
    float4v o;
#pragma unroll
    for (int j = 0; j < 4; ++j) o[j] = (float)a[j] + (float)b[j];
    ((float4v*)(out + t * DOUT))[l] = o;
}

extern "C" void kernel_launch(void* const* d_in, const int* in_sizes, int n_in,
                              void* d_out, int out_size, void* d_ws, size_t ws_size,
                              hipStream_t stream) {
    const float* x  = (const float*)d_in[0];
    const float* Wg = (const float*)d_in[1];
    const float* bg = (const float*)d_in[2];
    const float* W1 = (const float*)d_in[3];
    const float* b1 = (const float*)d_in[4];
    const float* W2 = (const float*)d_in[5];
    const float* b2 = (const float*)d_in[6];
    float* out = (float*)d_out;

    char* ws = (char*)d_ws;
    _Float16* p1  = (_Float16*)(ws + OFF_P1);
    _Float16* p2  = (_Float16*)(ws + OFF_P2);
    _Float16* xh  = (_Float16*)(ws + OFF_XH);
    _Float16* scr = (_Float16*)(ws + OFF_SCR);
    int* tidx     = (int*)(ws + OFF_TIDX);
    float* tw     = (float*)(ws + OFF_TW);
    int* stok     = (int*)(ws + OFF_STOK);
    float* swp    = (float*)(ws + OFF_SW);
    int* counts   = (int*)(ws + OFF_CNT);
    int* offsets  = (int*)(ws + OFF_OFFS);
    int* cursor   = (int*)(ws + OFF_CUR);
    int* tmap     = (int*)(ws + OFF_TMAP);
    int* tmc      = (int*)(ws + OFF_TMC);

    pack_kernel<<<dim3(2048), dim3(256), 0, stream>>>(W1, W2, p1, p2, counts);
    gate_kernel<<<dim3(512), dim3(256), 0, stream>>>(x, Wg, bg, xh, tidx, tw, counts);
    scan_kernel<<<dim3(1), dim3(64), 0, stream>>>(counts, offsets, cursor, tmap, tmc);
    scatter_kernel<<<dim3(256), dim3(256), 0, stream>>>(tidx, tw, cursor, stok, swp);
    mlp_kernel<<<dim3(1040), dim3(512), 0, stream>>>(xh, p1, p2, b1, b2, offsets,
                                                     stok, swp, tmap, tmc, scr);
    combine_kernel<<<dim3(8192), dim3(256), 0, stream>>>(scr, out);
}